// Round 5
// baseline (639.364 us; speedup 1.0000x reference)
//
#include <hip/hip_runtime.h>

typedef unsigned int u32;
typedef float f32x4 __attribute__((ext_vector_type(4)));
typedef short s16x8 __attribute__((ext_vector_type(8)));

#define LDA 136  // padded LDS row stride (bf16 elems) for k1

// workspace layout (bytes)
#define WQT_OFF 0ULL
#define WKT_OFF 32768ULL
#define WVT_OFF 65536ULL
#define OPWT_OFF 98304ULL
#define Q_OFF 114688ULL
#define K_OFF (Q_OFF + 8388608ULL)
#define VT_OFF (K_OFF + 8388608ULL)
#define GATE_OFF (VT_OFF + 8388608ULL)
// total ws need = GATE_OFF + 16 MiB ~= 40 MiB

__device__ __forceinline__ u32 f2bf(float f) {  // RNE float->bf16 bits
  u32 u = __float_as_uint(f);
  return (u + 0x7fffu + ((u >> 16) & 1u)) >> 16;
}

__device__ __forceinline__ void gl_lds16(const void* g, void* l) {
  __builtin_amdgcn_global_load_lds((const __attribute__((address_space(1))) void*)g,
                                   (__attribute__((address_space(3))) void*)l, 16, 0, 0);
}

// ---- k0: transpose weights to bf16; fold a_w * (1/sqrt(128)) * log2(e) into Wk^T ----
__global__ void k0_wt(const float* Wq, const float* Wk, const float* Wv,
                      const float* aw, const float* opW, char* ws) {
  int nt = blockIdx.x, part = blockIdx.y;
  int kksh = (nt == 3) ? 6 : 7;
  int KK = 1 << kksh;
  const float* S = (nt == 0) ? Wq : (nt == 1) ? Wk : (nt == 2) ? Wv : opW;
  unsigned short* D = (unsigned short*)(ws + (nt == 0 ? WQT_OFF : nt == 1 ? WKT_OFF : nt == 2 ? WVT_OFF : OPWT_OFF));
  int base = part * 8 * KK;
  for (int i = threadIdx.x; i < 8 * KK; i += 256) {
    int d = part * 8 + (i >> kksh), k = i & (KK - 1);
    float v = S[k * 128 + d];
    if (nt == 1) v *= aw[d] * 0.12751743f;  // (1/sqrt(128)) * log2(e)
    D[base + i] = (unsigned short)f2bf(v);
  }
}

// ---- k1: Q = h@Wq (bf16 [e][d]), K = h@Wk_scaled ([e][d]), Vt = (h@Wv)^T ([d][e]),
// ----     gate = sigmoid(op_emb@opW + op_b) (fp32 [e][d]) ----
__launch_bounds__(256, 2)
__global__ void k1_proj(const float* __restrict__ h, const float* __restrict__ op_emb,
                        const float* __restrict__ op_b, char* __restrict__ ws) {
  int nt = blockIdx.x, et = blockIdx.y;
  int kksh = (nt == 3) ? 6 : 7;
  int KK = 1 << kksh;
  __shared__ unsigned short bufA[128 * LDA];
  __shared__ unsigned short bufB[128 * LDA];
  unsigned short* wbuf = (nt == 2) ? bufB : bufA;
  unsigned short* xbuf = (nt == 2) ? bufA : bufB;
  const unsigned short* Wt = (const unsigned short*)(ws + (nt == 0 ? WQT_OFF : nt == 1 ? WKT_OFF : nt == 2 ? WVT_OFF : OPWT_OFF));
  {
    const uint4* Ws = (const uint4*)Wt;
    int cnt = 128 * KK / 8;
    for (int i = threadIdx.x; i < cnt; i += 256) {
      uint4 v = Ws[i];
      int r = (8 * i) >> kksh, c = (8 * i) & (KK - 1);
      *(uint4*)&wbuf[r * LDA + c] = v;
    }
  }
  {
    const float* X = (nt == 3) ? (op_emb + (size_t)et * 128 * 64) : (h + (size_t)et * 128 * 128);
    int cnt = 128 * KK / 4;
    for (int i = threadIdx.x; i < cnt; i += 256) {
      float4 v = *(const float4*)(X + 4 * i);
      int r = (4 * i) >> kksh, c = (4 * i) & (KK - 1);
      u32 lo = f2bf(v.x) | (f2bf(v.y) << 16);
      u32 hi = f2bf(v.z) | (f2bf(v.w) << 16);
      *(uint2*)&xbuf[r * LDA + c] = make_uint2(lo, hi);
    }
  }
  __syncthreads();
  int tid = threadIdx.x, w = tid >> 6, lane = tid & 63, l15 = lane & 15, q = lane >> 4;
  int wa = w >> 1, wb = w & 1;
  f32x4 acc[4][4];
#pragma unroll
  for (int a = 0; a < 4; a++)
#pragma unroll
    for (int bq = 0; bq < 4; bq++) acc[a][bq] = f32x4{0.f, 0.f, 0.f, 0.f};
  for (int ks = 0; ks < KK / 32; ks++) {
    s16x8 af[4], bf_[4];
#pragma unroll
    for (int mt = 0; mt < 4; mt++)
      af[mt] = *(const s16x8*)&bufA[(wa * 64 + mt * 16 + l15) * LDA + ks * 32 + q * 8];
#pragma unroll
    for (int n2 = 0; n2 < 4; n2++)
      bf_[n2] = *(const s16x8*)&bufB[(wb * 64 + n2 * 16 + l15) * LDA + ks * 32 + q * 8];
#pragma unroll
    for (int mt = 0; mt < 4; mt++)
#pragma unroll
      for (int n2 = 0; n2 < 4; n2++)
        acc[mt][n2] = __builtin_amdgcn_mfma_f32_16x16x32_bf16(af[mt], bf_[n2], acc[mt][n2], 0, 0, 0);
  }
  if (nt <= 1) {
    unsigned short* Dst = (unsigned short*)(ws + (nt == 0 ? Q_OFF : K_OFF));
#pragma unroll
    for (int mt = 0; mt < 4; mt++)
#pragma unroll
      for (int n2 = 0; n2 < 4; n2++) {
        int d0 = wa * 64 + mt * 16 + q * 4;
        int eg = et * 128 + wb * 64 + n2 * 16 + l15;
        f32x4 a = acc[mt][n2];
        u32 lo = f2bf(a[0]) | (f2bf(a[1]) << 16);
        u32 hi = f2bf(a[2]) | (f2bf(a[3]) << 16);
        *(uint2*)(Dst + (size_t)eg * 128 + d0) = make_uint2(lo, hi);
      }
  } else if (nt == 2) {
    unsigned short* Dst = (unsigned short*)(ws + VT_OFF);
    int b = et >> 4;
    int ein0 = (et & 15) * 128;
#pragma unroll
    for (int mt = 0; mt < 4; mt++)
#pragma unroll
      for (int n2 = 0; n2 < 4; n2++) {
        int e0b = ein0 + wa * 64 + mt * 16 + q * 4;
        int d = wb * 64 + n2 * 16 + l15;
        f32x4 a = acc[mt][n2];
        u32 lo = f2bf(a[0]) | (f2bf(a[1]) << 16);
        u32 hi = f2bf(a[2]) | (f2bf(a[3]) << 16);
        *(uint2*)(Dst + (size_t)b * 128 * 2048 + (size_t)d * 2048 + e0b) = make_uint2(lo, hi);
      }
  } else {
    float* Dst = (float*)(ws + GATE_OFF);
#pragma unroll
    for (int mt = 0; mt < 4; mt++)
#pragma unroll
      for (int n2 = 0; n2 < 4; n2++) {
        int d0 = wa * 64 + mt * 16 + q * 4;
        int eg = et * 128 + wb * 64 + n2 * 16 + l15;
        f32x4 a = acc[mt][n2];
        float4 g4;
        g4.x = 1.f / (1.f + __builtin_amdgcn_exp2f(-(a[0] + op_b[d0 + 0]) * 1.4426950f));
        g4.y = 1.f / (1.f + __builtin_amdgcn_exp2f(-(a[1] + op_b[d0 + 1]) * 1.4426950f));
        g4.z = 1.f / (1.f + __builtin_amdgcn_exp2f(-(a[2] + op_b[d0 + 2]) * 1.4426950f));
        g4.w = 1.f / (1.f + __builtin_amdgcn_exp2f(-(a[3] + op_b[d0 + 3]) * 1.4426950f));
        *(float4*)(Dst + (size_t)eg * 128 + d0) = g4;
      }
  }
}

// ---- k2: fused attention + gate + LayerNorm. 256-thread blocks, 64 e-rows each,
// ---- 512 blocks -> 2 blocks/CU (LDS 42 KB): sibling block hides barrier drains.
// ---- K tile single-buffered in LDS (DMA); Vt B-frags loaded global->VGPR (L2-resident).
__launch_bounds__(256, 2)
__global__ void k2_attn(const float* __restrict__ adj, const float* __restrict__ ln_g,
                        const float* __restrict__ ln_b, char* __restrict__ ws,
                        float* __restrict__ out) {
  __shared__ char smem[42240];
  char* Klds = smem;                      // 32768 B: K tile 128l x 128k, XOR-swizzled chunks
  float* sden = (float*)(smem + 41984);   // 64 denominators

  const int bid = blockIdx.x;
  const int xcd = bid & 7, slot = bid >> 3;         // 64 slots per XCD
  const int b = xcd * 2 + (slot >> 5);              // 2 batches per XCD (K/Vt L2-resident)
  const int e0 = (slot & 31) << 6;                  // 32 e-tiles of 64 rows

  const unsigned short* Qg = (const unsigned short*)(ws + Q_OFF) + ((size_t)b * 2048 + e0) * 128;
  const unsigned short* Kg = (const unsigned short*)(ws + K_OFF) + (size_t)b * 2048 * 128;
  const unsigned short* Vtg = (const unsigned short*)(ws + VT_OFF) + (size_t)b * 128 * 2048;
  const float* gateg = (const float*)(ws + GATE_OFF) + ((size_t)b * 2048 + e0) * 128;
  const float* adjg = adj + (size_t)b * 2048 * 2048 + (size_t)e0 * 2048;

  const int tid = threadIdx.x;
  const int w = tid >> 6, lane = tid & 63, l15 = lane & 15, q = lane >> 4;
  const int wh = w >> 1, we = w & 1;      // wh = l-half, we = e-half (32 rows)
  char* PLw = smem + 32768 + w * 2304;    // wave-private transform scratch (16 rows x 144 B)

  if (tid < 64) sden[tid] = 0.0f;

  // persistent Q B-frags: B[k=proj-dim][n=e]
  s16x8 qf[2][4];
#pragma unroll
  for (int et = 0; et < 2; et++) {
    const int e = we * 32 + et * 16 + l15;
#pragma unroll
    for (int ks = 0; ks < 4; ks++)
      qf[et][ks] = *(const s16x8*)(Qg + (size_t)e * 128 + ks * 32 + q * 8);
  }

  // O partials over this wave's l-half: C[m=e (2 et)][n=d (8 nt)]
  f32x4 oacc[2][8];
#pragma unroll
  for (int et = 0; et < 2; et++)
#pragma unroll
    for (int nt = 0; nt < 8; nt++) oacc[et][nt] = f32x4{0.f, 0.f, 0.f, 0.f};
  float dp0 = 0.0f, dp1 = 0.0f;
  float4 adjB[2][4];

  // prolog: stage K(0) (XOR chunk swizzle c^(r&15)); load adj(0)
#pragma unroll
  for (int j = 0; j < 8; j++) {
    int S = (j * 4 + w) * 64 + lane;
    int r = S >> 4, cp = S & 15, c = cp ^ (r & 15);
    gl_lds16(Kg + (size_t)r * 128 + (c << 3), Klds + (j * 4 + w) * 1024);
  }
#pragma unroll
  for (int et = 0; et < 2; et++) {
    const int e = we * 32 + et * 16 + l15;
#pragma unroll
    for (int lt = 0; lt < 4; lt++)
      adjB[et][lt] = *(const float4*)(adjg + (size_t)e * 2048 + wh * 64 + lt * 16 + q * 4);
  }

  for (int it = 0; it < 16; it++) {
    __syncthreads();  // [A] K(it) visible (vmcnt drain hidden by sibling block)
    float4 adjA[2][4];
#pragma unroll
    for (int et = 0; et < 2; et++)
#pragma unroll
      for (int lt = 0; lt < 4; lt++) adjA[et][lt] = adjB[et][lt];

    // GEMM1: St[l][e], A = K-frags (m=l), B = qf (n=e); scale pre-folded into K
    f32x4 sacc[4][2];
#pragma unroll
    for (int lt = 0; lt < 4; lt++)
#pragma unroll
      for (int et = 0; et < 2; et++) sacc[lt][et] = f32x4{0.f, 0.f, 0.f, 0.f};
#pragma unroll
    for (int ks = 0; ks < 4; ks++) {
      s16x8 kf[4];
#pragma unroll
      for (int lt = 0; lt < 4; lt++) {
        int l = wh * 64 + lt * 16 + l15;
        kf[lt] = *(const s16x8*)(Klds + l * 256 + (((ks * 4 + q) ^ l15) << 4));
      }
#pragma unroll
      for (int lt = 0; lt < 4; lt++)
#pragma unroll
        for (int et = 0; et < 2; et++)
          sacc[lt][et] = __builtin_amdgcn_mfma_f32_16x16x32_bf16(kf[lt], qf[et][ks], sacc[lt][et], 0, 0, 0);
    }
    __syncthreads();  // [B] all waves done reading Klds

    if (it < 15) {  // stage K(it+1) + prefetch adj(it+1): in flight until [A](it+1)
      const unsigned short* kb = Kg + (size_t)(it + 1) * 16384;
#pragma unroll
      for (int j = 0; j < 8; j++) {
        int S = (j * 4 + w) * 64 + lane;
        int r = S >> 4, cp = S & 15, c = cp ^ (r & 15);
        gl_lds16(kb + (size_t)r * 128 + (c << 3), Klds + (j * 4 + w) * 1024);
      }
      const float* ab = adjg + (size_t)(it + 1) * 128;
#pragma unroll
      for (int et = 0; et < 2; et++) {
        const int e = we * 32 + et * 16 + l15;
#pragma unroll
        for (int lt = 0; lt < 4; lt++)
          adjB[et][lt] = *(const float4*)(ab + (size_t)e * 2048 + wh * 64 + lt * 16 + q * 4);
      }
    }
    // prefetch Vt B-frags for ks2=0 (L2-resident; covered by elementwise VALU)
    const unsigned short* vrow = Vtg + (size_t)it * 128 + wh * 64 + q * 8;
    s16x8 vf0[8], vf1[8];
#pragma unroll
    for (int nt = 0; nt < 8; nt++)
      vf0[nt] = *(const s16x8*)(vrow + (size_t)(nt * 16 + l15) * 2048);

    // elementwise P = exp2(lrelu(s)*adj) (adj=0 -> 1), C-layout -> A-layout via wave LDS
    s16x8 af[2][2];
#pragma unroll
    for (int et = 0; et < 2; et++) {
      u32 pqw[4][2];
      float dsum = 0.0f;
#pragma unroll
      for (int lt = 0; lt < 4; lt++) {
        float4 aj = adjA[et][lt];
        f32x4 s = sacc[lt][et];
        float p0 = __builtin_amdgcn_exp2f(fmaxf(s[0], 0.2f * s[0]) * aj.x);
        float p1 = __builtin_amdgcn_exp2f(fmaxf(s[1], 0.2f * s[1]) * aj.y);
        float p2 = __builtin_amdgcn_exp2f(fmaxf(s[2], 0.2f * s[2]) * aj.z);
        float p3 = __builtin_amdgcn_exp2f(fmaxf(s[3], 0.2f * s[3]) * aj.w);
        dsum += (p0 + p1) + (p2 + p3);
        pqw[lt][0] = f2bf(p0) | (f2bf(p1) << 16);
        pqw[lt][1] = f2bf(p2) | (f2bf(p3) << 16);
      }
      if (et == 0) dp0 += dsum; else dp1 += dsum;
#pragma unroll
      for (int lt = 0; lt < 4; lt++)
        *(uint2*)(PLw + l15 * 144 + lt * 32 + q * 8) = make_uint2(pqw[lt][0], pqw[lt][1]);
      af[et][0] = *(const s16x8*)(PLw + l15 * 144 + q * 16);
      af[et][1] = *(const s16x8*)(PLw + l15 * 144 + 64 + q * 16);
    }
    // prefetch Vt for ks2=1 (flies under ks2=0 MFMAs)
#pragma unroll
    for (int nt = 0; nt < 8; nt++)
      vf1[nt] = *(const s16x8*)(vrow + 32 + (size_t)(nt * 16 + l15) * 2048);

    // GEMM2 (k-local over l-half): O[e][d] += P[e][kk] * Vt[d][kk]
#pragma unroll
    for (int et = 0; et < 2; et++)
#pragma unroll
      for (int nt = 0; nt < 8; nt++)
        oacc[et][nt] = __builtin_amdgcn_mfma_f32_16x16x32_bf16(af[et][0], vf0[nt], oacc[et][nt], 0, 0, 0);
#pragma unroll
    for (int et = 0; et < 2; et++)
#pragma unroll
      for (int nt = 0; nt < 8; nt++)
        oacc[et][nt] = __builtin_amdgcn_mfma_f32_16x16x32_bf16(af[et][1], vf1[nt], oacc[et][nt], 0, 0, 0);
  }

  // denominators (8 contributors per e: 4 q-lanes x 2 wh-waves)
  atomicAdd(&sden[we * 32 + l15], dp0);
  atomicAdd(&sden[we * 32 + 16 + l15], dp1);
  __syncthreads();

  // merge wh partials in O2 [e][d] fp32 (stride 132), overlays dead K/PL buffers
  float* O2 = (float*)smem;
  if (wh == 1) {
#pragma unroll
    for (int et = 0; et < 2; et++)
#pragma unroll
      for (int nt = 0; nt < 8; nt++) {
        const int eb = we * 32 + et * 16 + q * 4;
        const int d = nt * 16 + l15;
#pragma unroll
        for (int r = 0; r < 4; r++) O2[(eb + r) * 132 + d] = oacc[et][nt][r];
      }
  }
  __syncthreads();
  if (wh == 0) {
#pragma unroll
    for (int et = 0; et < 2; et++) {
      const int eb = we * 32 + et * 16 + q * 4;
      float inv[4];
#pragma unroll
      for (int r = 0; r < 4; r++) inv[r] = 1.0f / sden[eb + r];
#pragma unroll
      for (int nt = 0; nt < 8; nt++) {
        const int d = nt * 16 + l15;
#pragma unroll
        for (int r = 0; r < 4; r++) {
          int idx = (eb + r) * 132 + d;
          O2[idx] = (O2[idx] + oacc[et][nt][r]) * inv[r];
        }
      }
    }
  }
  __syncthreads();

  // LayerNorm: 4 threads per token, 32 features each (64 tokens, 256 threads)
  {
    const int e = tid >> 2, j = tid & 3;
    const float* row = O2 + e * 132 + j * 32;
    const float* gr = gateg + (size_t)e * 128 + j * 32;
    float4 x[8];
    float s1 = 0.f, s2 = 0.f;
#pragma unroll
    for (int i = 0; i < 8; i++) {
      float4 v = *(const float4*)(row + i * 4);
      float4 g = *(const float4*)(gr + i * 4);
      float4 hp;
      hp.x = v.x * g.x; hp.y = v.y * g.y; hp.z = v.z * g.z; hp.w = v.w * g.w;
      x[i] = hp;
      s1 += (hp.x + hp.y) + (hp.z + hp.w);
      s2 += (hp.x * hp.x + hp.y * hp.y) + (hp.z * hp.z + hp.w * hp.w);
    }
    s1 += __shfl_xor(s1, 1); s2 += __shfl_xor(s2, 1);
    s1 += __shfl_xor(s1, 2); s2 += __shfl_xor(s2, 2);
    const float mu = s1 * 0.0078125f;
    const float var = s2 * 0.0078125f - mu * mu;
    const float rs = rsqrtf(var + 1e-5f);
    float* orow = out + ((size_t)b * 2048 + e0 + e) * 128 + j * 32;
    const float* gg = ln_g + j * 32;
    const float* bb = ln_b + j * 32;
#pragma unroll
    for (int i = 0; i < 8; i++) {
      float4 gv = *(const float4*)(gg + i * 4);
      float4 bv = *(const float4*)(bb + i * 4);
      float4 o;
      o.x = (x[i].x - mu) * rs * gv.x + bv.x;
      o.y = (x[i].y - mu) * rs * gv.y + bv.y;
      o.z = (x[i].z - mu) * rs * gv.z + bv.z;
      o.w = (x[i].w - mu) * rs * gv.w + bv.w;
      *(float4*)(orow + i * 4) = o;
    }
  }
}

extern "C" void kernel_launch(void* const* d_in, const int* in_sizes, int n_in,
                              void* d_out, int out_size, void* d_ws, size_t ws_size,
                              hipStream_t stream) {
  const float* h = (const float*)d_in[0];
  const float* adj = (const float*)d_in[1];
  const float* op_emb = (const float*)d_in[2];
  const float* Wk = (const float*)d_in[3];
  const float* Wq = (const float*)d_in[4];
  const float* Wv = (const float*)d_in[5];
  const float* a_w = (const float*)d_in[6];
  const float* op_W = (const float*)d_in[7];
  const float* op_b = (const float*)d_in[8];
  const float* ln_g = (const float*)d_in[9];
  const float* ln_b = (const float*)d_in[10];
  char* ws = (char*)d_ws;
  float* out = (float*)d_out;

  k0_wt<<<dim3(4, 16), 256, 0, stream>>>(Wq, Wk, Wv, a_w, op_W, ws);
  k1_proj<<<dim3(4, 256), 256, 0, stream>>>(h, op_emb, op_b, ws);
  k2_attn<<<512, 256, 0, stream>>>(adj, ln_g, ln_b, ws, out);
}

// Round 7
// 448.366 us; speedup vs baseline: 1.4260x; 1.4260x over previous
//
#include <hip/hip_runtime.h>

typedef unsigned int u32;
typedef float f32x4 __attribute__((ext_vector_type(4)));
typedef short s16x8 __attribute__((ext_vector_type(8)));

#define LDA 136  // padded LDS row stride (bf16 elems) for k1

// workspace layout (bytes)
#define WQT_OFF 0ULL
#define WKT_OFF 32768ULL
#define WVT_OFF 65536ULL
#define OPWT_OFF 98304ULL
#define Q_OFF 114688ULL
#define K_OFF (Q_OFF + 8388608ULL)
#define VT_OFF (K_OFF + 8388608ULL)
#define GATE_OFF (VT_OFF + 8388608ULL)
// total ws need = GATE_OFF + 16 MiB ~= 40 MiB

__device__ __forceinline__ u32 f2bf(float f) {  // RNE float->bf16 bits
  u32 u = __float_as_uint(f);
  return (u + 0x7fffu + ((u >> 16) & 1u)) >> 16;
}

__device__ __forceinline__ void gl_lds16(const void* g, void* l) {
  __builtin_amdgcn_global_load_lds((const __attribute__((address_space(1))) void*)g,
                                   (__attribute__((address_space(3))) void*)l, 16, 0, 0);
}

// ---- k0: transpose weights to bf16; fold a_w * (1/sqrt(128)) * log2(e) into Wk^T ----
__global__ void k0_wt(const float* Wq, const float* Wk, const float* Wv,
                      const float* aw, const float* opW, char* ws) {
  int nt = blockIdx.x, part = blockIdx.y;
  int kksh = (nt == 3) ? 6 : 7;
  int KK = 1 << kksh;
  const float* S = (nt == 0) ? Wq : (nt == 1) ? Wk : (nt == 2) ? Wv : opW;
  unsigned short* D = (unsigned short*)(ws + (nt == 0 ? WQT_OFF : nt == 1 ? WKT_OFF : nt == 2 ? WVT_OFF : OPWT_OFF));
  int base = part * 8 * KK;
  for (int i = threadIdx.x; i < 8 * KK; i += 256) {
    int d = part * 8 + (i >> kksh), k = i & (KK - 1);
    float v = S[k * 128 + d];
    if (nt == 1) v *= aw[d] * 0.12751743f;  // (1/sqrt(128)) * log2(e)
    D[base + i] = (unsigned short)f2bf(v);
  }
}

// ---- k1: Q = h@Wq (bf16 [e][d]), K = h@Wk_scaled ([e][d]), Vt = (h@Wv)^T ([d][e]),
// ----     gate = sigmoid(op_emb@opW + op_b) (fp32 [e][d]) ----
__launch_bounds__(256, 2)
__global__ void k1_proj(const float* __restrict__ h, const float* __restrict__ op_emb,
                        const float* __restrict__ op_b, char* __restrict__ ws) {
  int nt = blockIdx.x, et = blockIdx.y;
  int kksh = (nt == 3) ? 6 : 7;
  int KK = 1 << kksh;
  __shared__ unsigned short bufA[128 * LDA];
  __shared__ unsigned short bufB[128 * LDA];
  unsigned short* wbuf = (nt == 2) ? bufB : bufA;
  unsigned short* xbuf = (nt == 2) ? bufA : bufB;
  const unsigned short* Wt = (const unsigned short*)(ws + (nt == 0 ? WQT_OFF : nt == 1 ? WKT_OFF : nt == 2 ? WVT_OFF : OPWT_OFF));
  {
    const uint4* Ws = (const uint4*)Wt;
    int cnt = 128 * KK / 8;
    for (int i = threadIdx.x; i < cnt; i += 256) {
      uint4 v = Ws[i];
      int r = (8 * i) >> kksh, c = (8 * i) & (KK - 1);
      *(uint4*)&wbuf[r * LDA + c] = v;
    }
  }
  {
    const float* X = (nt == 3) ? (op_emb + (size_t)et * 128 * 64) : (h + (size_t)et * 128 * 128);
    int cnt = 128 * KK / 4;
    for (int i = threadIdx.x; i < cnt; i += 256) {
      float4 v = *(const float4*)(X + 4 * i);
      int r = (4 * i) >> kksh, c = (4 * i) & (KK - 1);
      u32 lo = f2bf(v.x) | (f2bf(v.y) << 16);
      u32 hi = f2bf(v.z) | (f2bf(v.w) << 16);
      *(uint2*)&xbuf[r * LDA + c] = make_uint2(lo, hi);
    }
  }
  __syncthreads();
  int tid = threadIdx.x, w = tid >> 6, lane = tid & 63, l15 = lane & 15, q = lane >> 4;
  int wa = w >> 1, wb = w & 1;
  f32x4 acc[4][4];
#pragma unroll
  for (int a = 0; a < 4; a++)
#pragma unroll
    for (int bq = 0; bq < 4; bq++) acc[a][bq] = f32x4{0.f, 0.f, 0.f, 0.f};
  for (int ks = 0; ks < KK / 32; ks++) {
    s16x8 af[4], bf_[4];
#pragma unroll
    for (int mt = 0; mt < 4; mt++)
      af[mt] = *(const s16x8*)&bufA[(wa * 64 + mt * 16 + l15) * LDA + ks * 32 + q * 8];
#pragma unroll
    for (int n2 = 0; n2 < 4; n2++)
      bf_[n2] = *(const s16x8*)&bufB[(wb * 64 + n2 * 16 + l15) * LDA + ks * 32 + q * 8];
#pragma unroll
    for (int mt = 0; mt < 4; mt++)
#pragma unroll
      for (int n2 = 0; n2 < 4; n2++)
        acc[mt][n2] = __builtin_amdgcn_mfma_f32_16x16x32_bf16(af[mt], bf_[n2], acc[mt][n2], 0, 0, 0);
  }
  if (nt <= 1) {
    unsigned short* Dst = (unsigned short*)(ws + (nt == 0 ? Q_OFF : K_OFF));
#pragma unroll
    for (int mt = 0; mt < 4; mt++)
#pragma unroll
      for (int n2 = 0; n2 < 4; n2++) {
        int d0 = wa * 64 + mt * 16 + q * 4;
        int eg = et * 128 + wb * 64 + n2 * 16 + l15;
        f32x4 a = acc[mt][n2];
        u32 lo = f2bf(a[0]) | (f2bf(a[1]) << 16);
        u32 hi = f2bf(a[2]) | (f2bf(a[3]) << 16);
        *(uint2*)(Dst + (size_t)eg * 128 + d0) = make_uint2(lo, hi);
      }
  } else if (nt == 2) {
    unsigned short* Dst = (unsigned short*)(ws + VT_OFF);
    int b = et >> 4;
    int ein0 = (et & 15) * 128;
#pragma unroll
    for (int mt = 0; mt < 4; mt++)
#pragma unroll
      for (int n2 = 0; n2 < 4; n2++) {
        int e0b = ein0 + wa * 64 + mt * 16 + q * 4;
        int d = wb * 64 + n2 * 16 + l15;
        f32x4 a = acc[mt][n2];
        u32 lo = f2bf(a[0]) | (f2bf(a[1]) << 16);
        u32 hi = f2bf(a[2]) | (f2bf(a[3]) << 16);
        *(uint2*)(Dst + (size_t)b * 128 * 2048 + (size_t)d * 2048 + e0b) = make_uint2(lo, hi);
      }
  } else {
    float* Dst = (float*)(ws + GATE_OFF);
#pragma unroll
    for (int mt = 0; mt < 4; mt++)
#pragma unroll
      for (int n2 = 0; n2 < 4; n2++) {
        int d0 = wa * 64 + mt * 16 + q * 4;
        int eg = et * 128 + wb * 64 + n2 * 16 + l15;
        f32x4 a = acc[mt][n2];
        float4 g4;
        g4.x = 1.f / (1.f + __builtin_amdgcn_exp2f(-(a[0] + op_b[d0 + 0]) * 1.4426950f));
        g4.y = 1.f / (1.f + __builtin_amdgcn_exp2f(-(a[1] + op_b[d0 + 1]) * 1.4426950f));
        g4.z = 1.f / (1.f + __builtin_amdgcn_exp2f(-(a[2] + op_b[d0 + 2]) * 1.4426950f));
        g4.w = 1.f / (1.f + __builtin_amdgcn_exp2f(-(a[3] + op_b[d0 + 3]) * 1.4426950f));
        *(float4*)(Dst + (size_t)eg * 128 + d0) = g4;
      }
  }
}

// ---- k2: fused attention + gate + LayerNorm. 256 threads, 64 e-rows, 512 blocks.
// LDS = exactly 80 KB -> 2 blocks/CU; sibling block hides vmcnt(0) barrier drains.
// Tiles single-buffered, XOR chunk-swizzled (c ^ (row&15)): conflict-light b128 reads
// AND DMA-compatible (no padding). Softmax denominator computed exactly (eps=1e-5 is
// NOT negligible vs var(hp)~8e-5 - R6 post-mortem) but at epilogue-only cost.
__launch_bounds__(256, 2)
__global__ void k2_attn(const float* __restrict__ adj, const float* __restrict__ ln_g,
                        const float* __restrict__ ln_b, char* __restrict__ ws,
                        float* __restrict__ out) {
  __shared__ char smem[81920];
  char* Klds = smem;           // K tile [l=128][k=128] bf16, rows 256 B
  char* Vlds = smem + 32768;   // Vt tile [d=128][l=128] bf16, rows 256 B
  char* PL = smem + 65536;     // P [e=64][l=128] bf16, rows 256 B (shared across waves)

  const int bid = blockIdx.x;
  const int xcd = bid & 7, slot = bid >> 3;
  const int b = xcd * 2 + (slot >> 5);  // 2 batches per XCD: K/Vt stay L2-resident
  const int e0 = (slot & 31) << 6;

  const unsigned short* Qg = (const unsigned short*)(ws + Q_OFF) + ((size_t)b * 2048 + e0) * 128;
  const unsigned short* Kg = (const unsigned short*)(ws + K_OFF) + (size_t)b * 2048 * 128;
  const unsigned short* Vtg = (const unsigned short*)(ws + VT_OFF) + (size_t)b * 128 * 2048;
  const float* gateg = (const float*)(ws + GATE_OFF) + ((size_t)b * 2048 + e0) * 128;
  const float* adjg = adj + (size_t)b * 2048 * 2048 + (size_t)e0 * 2048;

  const int tid = threadIdx.x;
  const int w = tid >> 6, lane = tid & 63, l15 = lane & 15, q = lane >> 4;
  const int wh = w >> 1, we = w & 1;  // wh: l-half (GEMM1) / d-half (GEMM2); we: e-half

  // persistent Q B-frags: B[k=proj][n=e]
  s16x8 qf[2][4];
#pragma unroll
  for (int et = 0; et < 2; et++) {
    const int e = we * 32 + et * 16 + l15;
#pragma unroll
    for (int ks = 0; ks < 4; ks++)
      qf[et][ks] = *(const s16x8*)(Qg + (size_t)e * 128 + ks * 32 + q * 8);
  }

  // O accumulators: C[m=e (2 et)][n=d (4 dt, this wave's d-half)] - 32 VGPRs
  f32x4 oacc[2][4];
#pragma unroll
  for (int et = 0; et < 2; et++)
#pragma unroll
    for (int dt = 0; dt < 4; dt++) oacc[et][dt] = f32x4{0.f, 0.f, 0.f, 0.f};
  float dp0 = 0.0f, dp1 = 0.0f;  // denominator partials (this thread's P cells)
  float4 adjA[2][4], adjB[2][4];

  // prolog: DMA K(0), Vt(0); load adj(0)
#pragma unroll
  for (int j = 0; j < 8; j++) {
    int S = (j * 4 + w) * 64 + lane;
    int r = S >> 4, c = (S & 15) ^ (r & 15);
    gl_lds16(Kg + (size_t)r * 128 + (c << 3), Klds + (j * 4 + w) * 1024);
    gl_lds16(Vtg + (size_t)r * 2048 + (c << 3), Vlds + (j * 4 + w) * 1024);
  }
#pragma unroll
  for (int et = 0; et < 2; et++) {
    const int e = we * 32 + et * 16 + l15;
#pragma unroll
    for (int lt = 0; lt < 4; lt++)
      adjB[et][lt] = *(const float4*)(adjg + (size_t)e * 2048 + wh * 64 + lt * 16 + q * 4);
  }

#pragma unroll 1
  for (int it = 0; it < 16; it++) {
    __syncthreads();  // [A] K(it)/Vt(it) DMA drained; PL(it-1) consumed
#pragma unroll
    for (int et = 0; et < 2; et++)
#pragma unroll
      for (int lt = 0; lt < 4; lt++) adjA[et][lt] = adjB[et][lt];
    if (it < 15) {  // adj(it+1) into regs; in flight under GEMM1
      const float* ab = adjg + (size_t)(it + 1) * 128;
#pragma unroll
      for (int et = 0; et < 2; et++) {
        const int e = we * 32 + et * 16 + l15;
#pragma unroll
        for (int lt = 0; lt < 4; lt++)
          adjB[et][lt] = *(const float4*)(ab + (size_t)e * 2048 + wh * 64 + lt * 16 + q * 4);
      }
    }

    // GEMM1: St[l][e] = K_tile @ Q^T (scale/log2e pre-folded into K)
    f32x4 sacc[4][2];
#pragma unroll
    for (int lt = 0; lt < 4; lt++)
#pragma unroll
      for (int et = 0; et < 2; et++) sacc[lt][et] = f32x4{0.f, 0.f, 0.f, 0.f};
#pragma unroll
    for (int ks = 0; ks < 4; ks++) {
      s16x8 kf[4];
#pragma unroll
      for (int lt = 0; lt < 4; lt++) {
        int l = wh * 64 + lt * 16 + l15;
        kf[lt] = *(const s16x8*)(Klds + l * 256 + (((ks * 4 + q) ^ l15) << 4));
      }
#pragma unroll
      for (int lt = 0; lt < 4; lt++)
#pragma unroll
        for (int et = 0; et < 2; et++)
          sacc[lt][et] = __builtin_amdgcn_mfma_f32_16x16x32_bf16(kf[lt], qf[et][ks], sacc[lt][et], 0, 0, 0);
    }

    // P = exp2(lrelu(s)*adj) (adj=0 -> 1); accumulate denom; pack bf16 -> PL (swizzled)
#pragma unroll
    for (int et = 0; et < 2; et++) {
      const int e = we * 32 + et * 16 + l15;
      float dsum = 0.0f;
#pragma unroll
      for (int lt = 0; lt < 4; lt++) {
        float4 aj = adjA[et][lt];
        f32x4 s = sacc[lt][et];
        float p0 = __builtin_amdgcn_exp2f(fmaxf(s[0], 0.2f * s[0]) * aj.x);
        float p1 = __builtin_amdgcn_exp2f(fmaxf(s[1], 0.2f * s[1]) * aj.y);
        float p2 = __builtin_amdgcn_exp2f(fmaxf(s[2], 0.2f * s[2]) * aj.z);
        float p3 = __builtin_amdgcn_exp2f(fmaxf(s[3], 0.2f * s[3]) * aj.w);
        dsum += (p0 + p1) + (p2 + p3);
        // l = wh*64 + lt*16 + q*4 -> chunk = l>>3, half = q&1
        int chunk = wh * 8 + lt * 2 + (q >> 1);
        *(uint2*)(PL + e * 256 + ((chunk ^ l15) << 4) + (q & 1) * 8) =
            make_uint2(f2bf(p0) | (f2bf(p1) << 16), f2bf(p2) | (f2bf(p3) << 16));
      }
      if (et == 0) dp0 += dsum; else dp1 += dsum;
    }
    __syncthreads();  // [B] PL ready; Klds free (all GEMM1 reads done)

    if (it < 15) {  // DMA K(it+1); in flight until [A](it+1)
      const unsigned short* kb = Kg + (size_t)(it + 1) * 16384;
#pragma unroll
      for (int j = 0; j < 8; j++) {
        int S = (j * 4 + w) * 64 + lane;
        int r = S >> 4, c = (S & 15) ^ (r & 15);
        gl_lds16(kb + (size_t)r * 128 + (c << 3), Klds + (j * 4 + w) * 1024);
      }
    }

    // GEMM2: O[e][d-half] += P[e][l] * Vt[d][l], k = all 128 l
#pragma unroll
    for (int ks = 0; ks < 4; ks++) {
      s16x8 af[2], vf[4];
#pragma unroll
      for (int et = 0; et < 2; et++) {
        const int e = we * 32 + et * 16 + l15;
        af[et] = *(const s16x8*)(PL + e * 256 + (((ks * 4 + q) ^ l15) << 4));
      }
#pragma unroll
      for (int dt = 0; dt < 4; dt++) {
        int d = wh * 64 + dt * 16 + l15;
        vf[dt] = *(const s16x8*)(Vlds + d * 256 + (((ks * 4 + q) ^ l15) << 4));
      }
#pragma unroll
      for (int et = 0; et < 2; et++)
#pragma unroll
        for (int dt = 0; dt < 4; dt++)
          oacc[et][dt] = __builtin_amdgcn_mfma_f32_16x16x32_bf16(af[et], vf[dt], oacc[et][dt], 0, 0, 0);
    }
    __syncthreads();  // [C] Vlds free (all GEMM2 reads done); PL free at next [A]

    if (it < 15) {  // DMA Vt(it+1); drains at [A](it+1) under sibling cover
      const unsigned short* vb = Vtg + (size_t)(it + 1) * 128;
#pragma unroll
      for (int j = 0; j < 8; j++) {
        int S = (j * 4 + w) * 64 + lane;
        int r = S >> 4, c = (S & 15) ^ (r & 15);
        gl_lds16(vb + (size_t)r * 2048 + (c << 3), Vlds + (j * 4 + w) * 1024);
      }
    }
  }

  // ---- epilogue ----
  // sden overlays the now-dead PL region (LDS total stays 81920 -> 2 blocks/CU)
  float* sden = (float*)(smem + 65536);
  if (tid < 64) sden[tid] = 0.0f;
  __syncthreads();  // sden zeroed (also: all PL reads done before overlay write)
  atomicAdd(&sden[we * 32 + l15], dp0);        // 8 contributors per e (2 wh x 4 q)
  atomicAdd(&sden[we * 32 + 16 + l15], dp1);

  // O2 [e=64][d=128] fp32 stride 132 overlays dead K/V tiles (33.8 KB)
  float* O2 = (float*)smem;
#pragma unroll
  for (int et = 0; et < 2; et++)
#pragma unroll
    for (int dt = 0; dt < 4; dt++) {
      const int eb = we * 32 + et * 16 + q * 4;
      const int d = wh * 64 + dt * 16 + l15;
      f32x4 v = oacc[et][dt];
#pragma unroll
      for (int r = 0; r < 4; r++) O2[(eb + r) * 132 + d] = v[r];
    }
  __syncthreads();  // O2 + sden visible

  // hp = gate * (O/den); LayerNorm; store. 4 threads per token, 32 features each.
  {
    const int e = tid >> 2, j = tid & 3;
    const float inv = 1.0f / sden[e];
    const float* row = O2 + e * 132 + j * 32;
    const float* gr = gateg + (size_t)e * 128 + j * 32;
    float4 x[8];
    float s1 = 0.f, s2 = 0.f;
#pragma unroll
    for (int i = 0; i < 8; i++) {
      float4 v = *(const float4*)(row + i * 4);
      float4 g = *(const float4*)(gr + i * 4);
      float4 hp;
      hp.x = v.x * inv * g.x; hp.y = v.y * inv * g.y;
      hp.z = v.z * inv * g.z; hp.w = v.w * inv * g.w;
      x[i] = hp;
      s1 += (hp.x + hp.y) + (hp.z + hp.w);
      s2 += (hp.x * hp.x + hp.y * hp.y) + (hp.z * hp.z + hp.w * hp.w);
    }
    s1 += __shfl_xor(s1, 1); s2 += __shfl_xor(s2, 1);
    s1 += __shfl_xor(s1, 2); s2 += __shfl_xor(s2, 2);
    const float mu = s1 * 0.0078125f;
    const float var = s2 * 0.0078125f - mu * mu;
    const float rs = rsqrtf(var + 1e-5f);
    float* orow = out + ((size_t)b * 2048 + e0 + e) * 128 + j * 32;
    const float* gg = ln_g + j * 32;
    const float* bb = ln_b + j * 32;
#pragma unroll
    for (int i = 0; i < 8; i++) {
      float4 gv = *(const float4*)(gg + i * 4);
      float4 bv = *(const float4*)(bb + i * 4);
      float4 o;
      o.x = (x[i].x - mu) * rs * gv.x + bv.x;
      o.y = (x[i].y - mu) * rs * gv.y + bv.y;
      o.z = (x[i].z - mu) * rs * gv.z + bv.z;
      o.w = (x[i].w - mu) * rs * gv.w + bv.w;
      *(float4*)(orow + i * 4) = o;
    }
  }
}

extern "C" void kernel_launch(void* const* d_in, const int* in_sizes, int n_in,
                              void* d_out, int out_size, void* d_ws, size_t ws_size,
                              hipStream_t stream) {
  const float* h = (const float*)d_in[0];
  const float* adj = (const float*)d_in[1];
  const float* op_emb = (const float*)d_in[2];
  const float* Wk = (const float*)d_in[3];
  const float* Wq = (const float*)d_in[4];
  const float* Wv = (const float*)d_in[5];
  const float* a_w = (const float*)d_in[6];
  const float* op_W = (const float*)d_in[7];
  const float* op_b = (const float*)d_in[8];
  const float* ln_g = (const float*)d_in[9];
  const float* ln_b = (const float*)d_in[10];
  char* ws = (char*)d_ws;
  float* out = (float*)d_out;

  k0_wt<<<dim3(4, 16), 256, 0, stream>>>(Wq, Wk, Wv, a_w, op_W, ws);
  k1_proj<<<dim3(4, 256), 256, 0, stream>>>(h, op_emb, op_b, ws);
  k2_attn<<<512, 256, 0, stream>>>(adj, ln_g, ln_b, ws, out);
}